// Round 1
// baseline (589.024 us; speedup 1.0000x reference)
//
#include <hip/hip_runtime.h>

// Problem constants (from reference setup_inputs): B=2, H=W=128.
#define B_ITEMS 2
#define W_IMG   128
#define N_PTS   16384          // H*W
#define TA      4              // A-points per thread (register tile)
#define BCH     8              // B-scan chunks per slice (parallelism)

// ---------------------------------------------------------------------------
// Kernel 1: unproject pred -> xyz, apply validity (mask>0 && x+y+z != 0),
// compact valid pred/gt points into float4 arrays via atomic counters.
// ---------------------------------------------------------------------------
__global__ void prep_kernel(const float* __restrict__ pred,
                            const float* __restrict__ gt,
                            const int*   __restrict__ mask,
                            const float* fxp, const float* fyp,
                            const float* cxp, const float* cyp,
                            int* __restrict__ cnt,          // [0..1]=np, [2..3]=ng
                            float4* __restrict__ p4,        // [B][N]
                            float4* __restrict__ g4) {      // [B][N]
    int t = blockIdx.x * blockDim.x + threadIdx.x;
    if (t >= B_ITEMS * N_PTS) return;
    int b   = t >> 14;             // / N_PTS
    int idx = t & (N_PTS - 1);

    float fx = *fxp, fy = *fyp, cx = *cxp, cy = *cyp;
    int   mv = mask[t];
    float u  = (float)(idx & (W_IMG - 1));
    float v  = (float)(idx >> 7);
    float z  = pred[t];
    float x  = (u - cx) / fx * z;
    float y  = (v - cy) / fy * z;

    if (mv > 0 && ((x + y) + z) != 0.0f) {
        int pos = atomicAdd(&cnt[b], 1);
        p4[b * N_PTS + pos] = make_float4(x, y, z, 0.0f);
    }

    float gx = gt[(b * 3 + 0) * N_PTS + idx];
    float gy = gt[(b * 3 + 1) * N_PTS + idx];
    float gz = gt[(b * 3 + 2) * N_PTS + idx];
    if (mv > 0 && ((gx + gy) + gz) != 0.0f) {
        int pos = atomicAdd(&cnt[2 + b], 1);
        g4[b * N_PTS + pos] = make_float4(gx, gy, gz, 0.0f);
    }
}

// ---------------------------------------------------------------------------
// Kernel 2: chamfer min-distance. Grid (A_tiles=64, BCH, slices=4), block=64.
// slice = b*2 + dir. Each thread owns TA consecutive A-points in registers,
// scans its B-chunk with wave-uniform loads (scalar-load friendly), keeps TA
// independent running mins, then atomicMin-combines into the global min array
// (uint bit-compare valid: all d >= 0).
// ---------------------------------------------------------------------------
__global__ __launch_bounds__(64) void chamfer_kernel(
        const int*    __restrict__ cnt,
        const float4* __restrict__ p4,
        const float4* __restrict__ g4,
        unsigned int* __restrict__ minarr) {   // [4][N_PTS]
    int s   = blockIdx.z;
    int b   = s >> 1;
    int dir = s & 1;
    int na, nb;
    const float4 *A, *Bp;
    if (dir == 0) { na = cnt[b];     nb = cnt[2 + b]; A = p4 + b * N_PTS; Bp = g4 + b * N_PTS; }
    else          { na = cnt[2 + b]; nb = cnt[b];     A = g4 + b * N_PTS; Bp = p4 + b * N_PTS; }
    if (nb == 0) return;                      // has_other == false -> contributes 0
    int base = blockIdx.x * (64 * TA);
    if (base >= na) return;

    int i0 = base + threadIdx.x * TA;
    float ax[TA], ay[TA], az[TA], m[TA];
#pragma unroll
    for (int t = 0; t < TA; t++) {
        float4 a = A[i0 + t];                 // may be junk if i0+t >= na; gated at write
        ax[t] = a.x; ay[t] = a.y; az[t] = a.z;
        m[t] = 3.4e38f;
    }

    int c  = blockIdx.y;
    int kb = (int)(((long long)nb * c)       / BCH);
    int ke = (int)(((long long)nb * (c + 1)) / BCH);
    for (int k = kb; k < ke; ++k) {
        float4 g = Bp[k];                     // wave-uniform address
#pragma unroll
        for (int t = 0; t < TA; t++) {
            float dx = ax[t] - g.x;
            float dy = ay[t] - g.y;
            float dz = az[t] - g.z;
            float d  = fmaf(dx, dx, fmaf(dy, dy, dz * dz));
            m[t] = fminf(m[t], d);
        }
    }

    unsigned int* mslice = minarr + s * N_PTS;
#pragma unroll
    for (int t = 0; t < TA; t++) {
        int i = i0 + t;
        if (i < na) atomicMin(&mslice[i], __float_as_uint(m[t]));
    }
}

// ---------------------------------------------------------------------------
// Kernel 3: gather mins, gate on (i < na && nb > 0), block-reduce, /B.
// ---------------------------------------------------------------------------
__global__ void sum_kernel(const int* __restrict__ cnt,
                           const unsigned int* __restrict__ minarr,
                           float* __restrict__ out) {
    int s   = blockIdx.y;
    int b   = s >> 1;
    int dir = s & 1;
    int na  = (dir == 0) ? cnt[b]     : cnt[2 + b];
    int nb  = (dir == 0) ? cnt[2 + b] : cnt[b];
    int i   = blockIdx.x * 256 + threadIdx.x;

    float v = 0.0f;
    if (i < na && nb > 0) v = __uint_as_float(minarr[s * N_PTS + i]);

    for (int off = 32; off > 0; off >>= 1) v += __shfl_down(v, off, 64);

    __shared__ float wsum[4];
    int lane = threadIdx.x & 63, wid = threadIdx.x >> 6;
    if (lane == 0) wsum[wid] = v;
    __syncthreads();
    if (threadIdx.x == 0) {
        float total = wsum[0] + wsum[1] + wsum[2] + wsum[3];
        atomicAdd(out, total * (1.0f / B_ITEMS));
    }
}

extern "C" void kernel_launch(void* const* d_in, const int* in_sizes, int n_in,
                              void* d_out, int out_size, void* d_ws, size_t ws_size,
                              hipStream_t stream) {
    const float* pred = (const float*)d_in[0];
    const float* gt   = (const float*)d_in[1];
    const int*   mask = (const int*)  d_in[2];
    const float* fx   = (const float*)d_in[3];
    const float* fy   = (const float*)d_in[4];
    const float* cx   = (const float*)d_in[5];
    const float* cy   = (const float*)d_in[6];
    float* out = (float*)d_out;

    // ws layout: [0,16) counters | [256, +512K) p4 | +512K g4 | +256K minarr
    char* ws = (char*)d_ws;
    int*          cnt    = (int*)ws;
    float4*       p4     = (float4*)(ws + 256);
    float4*       g4     = (float4*)(ws + 256 + (size_t)B_ITEMS * N_PTS * 16);
    unsigned int* minarr = (unsigned int*)(ws + 256 + (size_t)2 * B_ITEMS * N_PTS * 16);

    hipMemsetAsync(cnt, 0, 16, stream);
    hipMemsetAsync(minarr, 0xFF, (size_t)4 * N_PTS * 4, stream);   // +inf-ish uint max
    hipMemsetAsync(out, 0, 4, stream);

    prep_kernel<<<dim3((B_ITEMS * N_PTS + 255) / 256), 256, 0, stream>>>(
        pred, gt, mask, fx, fy, cx, cy, cnt, p4, g4);

    chamfer_kernel<<<dim3(N_PTS / (64 * TA), BCH, 2 * B_ITEMS), 64, 0, stream>>>(
        cnt, p4, g4, minarr);

    sum_kernel<<<dim3(N_PTS / 256, 2 * B_ITEMS), 256, 0, stream>>>(cnt, minarr, out);
}

// Round 2
// 150.894 us; speedup vs baseline: 3.9036x; 3.9036x over previous
//
#include <hip/hip_runtime.h>

// Problem constants (from reference setup_inputs): B=2, H=W=128.
#define B_ITEMS 2
#define W_IMG   128
#define N_PTS   16384          // H*W
#define BLK     256            // chamfer block size
#define TA      4              // A-points per thread (strided by BLK)
#define TILE_A  (BLK * TA)     // 1024 A-points per block
#define BCH     16             // B-scan chunks per slice (parallelism)

// ---------------------------------------------------------------------------
// Kernel 1: unproject pred -> xyz, validity (mask>0 && x+y+z != 0), compact
// valid pred/gt points via WAVE-BALLOT compaction: one atomicAdd per wave per
// counter (R1 post-mortem: per-thread same-address atomics cost 372 us).
// Also initializes minarr to +inf bits (folds away a memset dispatch).
// Grid is exactly B*N/256 blocks -> all 64 lanes of every wave active.
// ---------------------------------------------------------------------------
__global__ __launch_bounds__(256) void prep_kernel(
        const float* __restrict__ pred,
        const float* __restrict__ gt,
        const int*   __restrict__ mask,
        const float* fxp, const float* fyp,
        const float* cxp, const float* cyp,
        int* __restrict__ cnt,          // [0..1]=np, [2..3]=ng
        float4* __restrict__ p4,        // [B][N]
        float4* __restrict__ g4,        // [B][N]
        unsigned int* __restrict__ minarr) {  // [4][N]
    int t    = blockIdx.x * 256 + threadIdx.x;
    int b    = t >> 14;             // / N_PTS
    int idx  = t & (N_PTS - 1);
    int lane = threadIdx.x & 63;

    float fx = *fxp, fy = *fyp, cx = *cxp, cy = *cyp;
    int   mv = mask[t];
    float u  = (float)(idx & (W_IMG - 1));
    float v  = (float)(idx >> 7);
    float z  = pred[t];
    float x  = (u - cx) / fx * z;
    float y  = (v - cy) / fy * z;

    bool vp = (mv > 0) && (((x + y) + z) != 0.0f);
    {
        unsigned long long bal = __ballot(vp);
        int nw  = __popcll(bal);
        int pre = __popcll(bal & ((1ull << lane) - 1ull));
        int basep = 0;
        if (lane == 0 && nw) basep = atomicAdd(&cnt[b], nw);
        basep = __shfl(basep, 0, 64);
        if (vp) p4[b * N_PTS + basep + pre] = make_float4(x, y, z, 0.0f);
    }

    float gx = gt[(b * 3 + 0) * N_PTS + idx];
    float gy = gt[(b * 3 + 1) * N_PTS + idx];
    float gz = gt[(b * 3 + 2) * N_PTS + idx];
    bool vg = (mv > 0) && (((gx + gy) + gz) != 0.0f);
    {
        unsigned long long bal = __ballot(vg);
        int nw  = __popcll(bal);
        int pre = __popcll(bal & ((1ull << lane) - 1ull));
        int baseg = 0;
        if (lane == 0 && nw) baseg = atomicAdd(&cnt[2 + b], nw);
        baseg = __shfl(baseg, 0, 64);
        if (vg) g4[b * N_PTS + baseg + pre] = make_float4(gx, gy, gz, 0.0f);
    }

    // minarr init (+inf bits) for both directions of this item
    minarr[(b * 2 + 0) * N_PTS + idx] = 0xFFFFFFFFu;
    minarr[(b * 2 + 1) * N_PTS + idx] = 0xFFFFFFFFu;
}

// ---------------------------------------------------------------------------
// Kernel 2: chamfer min-distance. Grid (16, BCH, 4 slices), block=256.
// Each thread owns TA=4 A-points strided by BLK (coalesced loads & atomicMin).
// B-chunk staged through LDS in 256-point tiles; inner reads are same-address
// broadcasts (conflict-free). 4 independent min-accumulators give ILP.
// ---------------------------------------------------------------------------
__global__ __launch_bounds__(256) void chamfer_kernel(
        const int*    __restrict__ cnt,
        const float4* __restrict__ p4,
        const float4* __restrict__ g4,
        unsigned int* __restrict__ minarr) {   // [4][N]
    int s   = blockIdx.z;
    int b   = s >> 1;
    int dir = s & 1;
    int na, nb;
    const float4 *A, *Bp;
    if (dir == 0) { na = cnt[b];     nb = cnt[2 + b]; A = p4 + b * N_PTS; Bp = g4 + b * N_PTS; }
    else          { na = cnt[2 + b]; nb = cnt[b];     A = g4 + b * N_PTS; Bp = p4 + b * N_PTS; }
    if (nb == 0) return;                      // has_other == false -> contributes 0
    int base = blockIdx.x * TILE_A;
    if (base >= na) return;

    __shared__ float4 sB[BLK];

    float ax[TA], ay[TA], az[TA], m[TA];
#pragma unroll
    for (int t = 0; t < TA; t++) {
        // i may exceed na (junk read within the N_PTS-capacity array); the
        // final atomicMin is gated on i < na, so junk only pollutes a dead m[t].
        float4 a = A[base + (int)threadIdx.x + t * BLK];
        ax[t] = a.x; ay[t] = a.y; az[t] = a.z;
        m[t] = 3.4e38f;
    }

    int c  = blockIdx.y;
    int kb = nb * c / BCH;
    int ke = nb * (c + 1) / BCH;
    for (int k0 = kb; k0 < ke; k0 += BLK) {
        __syncthreads();                       // previous tile fully consumed
        int kk = k0 + (int)threadIdx.x;
        if (kk < ke) sB[threadIdx.x] = Bp[kk];
        __syncthreads();
        int lim = min(BLK, ke - k0);
        if (lim == BLK) {
#pragma unroll 4
            for (int j = 0; j < BLK; ++j) {
                float4 g = sB[j];
#pragma unroll
                for (int t = 0; t < TA; t++) {
                    float dx = ax[t] - g.x;
                    float dy = ay[t] - g.y;
                    float dz = az[t] - g.z;
                    float d  = fmaf(dx, dx, fmaf(dy, dy, dz * dz));
                    m[t] = fminf(m[t], d);
                }
            }
        } else {
            for (int j = 0; j < lim; ++j) {
                float4 g = sB[j];
#pragma unroll
                for (int t = 0; t < TA; t++) {
                    float dx = ax[t] - g.x;
                    float dy = ay[t] - g.y;
                    float dz = az[t] - g.z;
                    float d  = fmaf(dx, dx, fmaf(dy, dy, dz * dz));
                    m[t] = fminf(m[t], d);
                }
            }
        }
    }

    unsigned int* ms = minarr + s * N_PTS;
#pragma unroll
    for (int t = 0; t < TA; t++) {
        int i = base + (int)threadIdx.x + t * BLK;
        if (i < na) atomicMin(&ms[i], __float_as_uint(m[t]));   // d >= 0 -> uint order ok
    }
}

// ---------------------------------------------------------------------------
// Kernel 3: gather mins, gate on (i < na && nb > 0), block-reduce, /B.
// ---------------------------------------------------------------------------
__global__ __launch_bounds__(256) void sum_kernel(
        const int* __restrict__ cnt,
        const unsigned int* __restrict__ minarr,
        float* __restrict__ out) {
    int s   = blockIdx.y;
    int b   = s >> 1;
    int dir = s & 1;
    int na  = (dir == 0) ? cnt[b]     : cnt[2 + b];
    int nb  = (dir == 0) ? cnt[2 + b] : cnt[b];
    int i   = blockIdx.x * 256 + threadIdx.x;

    float v = 0.0f;
    if (i < na && nb > 0) v = __uint_as_float(minarr[s * N_PTS + i]);

    for (int off = 32; off > 0; off >>= 1) v += __shfl_down(v, off, 64);

    __shared__ float wsum[4];
    int lane = threadIdx.x & 63, wid = threadIdx.x >> 6;
    if (lane == 0) wsum[wid] = v;
    __syncthreads();
    if (threadIdx.x == 0) {
        float total = wsum[0] + wsum[1] + wsum[2] + wsum[3];
        atomicAdd(out, total * (1.0f / B_ITEMS));
    }
}

extern "C" void kernel_launch(void* const* d_in, const int* in_sizes, int n_in,
                              void* d_out, int out_size, void* d_ws, size_t ws_size,
                              hipStream_t stream) {
    const float* pred = (const float*)d_in[0];
    const float* gt   = (const float*)d_in[1];
    const int*   mask = (const int*)  d_in[2];
    const float* fx   = (const float*)d_in[3];
    const float* fy   = (const float*)d_in[4];
    const float* cx   = (const float*)d_in[5];
    const float* cy   = (const float*)d_in[6];
    float* out = (float*)d_out;

    // ws layout: [0,256) counters | p4 512K | g4 512K | minarr 256K
    char* ws = (char*)d_ws;
    int*          cnt    = (int*)ws;
    float4*       p4     = (float4*)(ws + 256);
    float4*       g4     = (float4*)(ws + 256 + (size_t)B_ITEMS * N_PTS * 16);
    unsigned int* minarr = (unsigned int*)(ws + 256 + (size_t)2 * B_ITEMS * N_PTS * 16);

    hipMemsetAsync(cnt, 0, 16, stream);
    hipMemsetAsync(out, 0, 4, stream);

    prep_kernel<<<dim3(B_ITEMS * N_PTS / 256), 256, 0, stream>>>(
        pred, gt, mask, fx, fy, cx, cy, cnt, p4, g4, minarr);

    chamfer_kernel<<<dim3(N_PTS / TILE_A, BCH, 2 * B_ITEMS), BLK, 0, stream>>>(
        cnt, p4, g4, minarr);

    sum_kernel<<<dim3(N_PTS / 256, 2 * B_ITEMS), 256, 0, stream>>>(cnt, minarr, out);
}